// Round 3
// baseline (400.608 us; speedup 1.0000x reference)
//
#include <hip/hip_runtime.h>
#include <cstdint>
#include <cstddef>

// Problem constants (from reference)
#define BB      512
#define CC      256
#define KXX     6
#define KZZ     22
#define HO      17                 // 22 - 6 + 1
#define OUTHW   (HO * HO)          // 289
#define ZCH     (KZZ * KZZ)        // 484 floats per (b,c) of z
#define XCH     (KXX * KXX)        // 36 floats per (b,c) of x

// Tiling
#define CHUNK_C   8                          // channels staged per chunk
#define NCHUNK    (CC / CHUNK_C)             // 32
#define ZCHUNK    (CHUNK_C * ZCH)            // 3872 floats = 15488 B
#define XCHUNK    (CHUNK_C * XCH)            // 288 floats  = 1152 B
#define NT        320                        // 5 waves
#define NBUF      3                          // 2-chunk-deep prefetch

typedef const __attribute__((address_space(1))) void* gptr_t;
typedef __attribute__((address_space(3))) void* lptr_t;

// Counted vmcnt wait: keeps prefetched chunks in flight across barriers
// (T4: never drain to 0 in the main loop). "memory" clobber orders the
// surrounding ds_read/global_load_lds against it.
#define WAITVM(N) asm volatile("s_waitcnt vmcnt(" #N ")" ::: "memory")

// Async global->LDS. LDS dest is WAVE-UNIFORM base; HW scatters lane i to
// base + i*size. Global addr is per-lane.
__device__ __forceinline__ void cp16_async(void* lds_base, const void* gsrc) {
  __builtin_amdgcn_global_load_lds((gptr_t)gsrc, (lptr_t)lds_base, 16, 0, 0);
}
__device__ __forceinline__ void cp4_async(void* lds_base, const void* gsrc) {
  __builtin_amdgcn_global_load_lds((gptr_t)gsrc, (lptr_t)lds_base, 4, 0, 0);
}

// Stage one chunk: z = 15488 B (15 x 1024 B + 128 B tail),
//                  x = 1152 B  (1 x 1024 B + 128 B tail).
// vmcnt instructions per wave per chunk: waves 0,1,2 -> 4; waves 3,4 -> 3.
__device__ __forceinline__ void stage_chunk(float* zdst, float* xdst,
                                            const float* zsrc, const float* xsrc,
                                            int wave, int lane) {
  char* zd = (char*)zdst;
  const char* zs = (const char*)zsrc;
#pragma unroll
  for (int i = 0; i < 3; ++i) {               // 15 full 1 KiB groups, 3 per wave
    const int grp = wave * 3 + i;
    cp16_async(zd + grp * 1024, zs + grp * 1024 + lane * 16);
  }
  if (wave == 0) {
    if (lane < 32) cp4_async(zd + 15360, zs + 15360 + lane * 4);   // z tail 128 B
  } else if (wave == 1) {
    cp16_async((char*)xdst, (const char*)xsrc + lane * 16);        // x 1024 B
  } else if (wave == 2) {
    if (lane < 32) cp4_async((char*)xdst + 1024, (const char*)xsrc + 1024 + lane * 4);
  }
}

__global__ __launch_bounds__(NT, 2) void corr_kernel(const float* __restrict__ x,
                                                     const float* __restrict__ z,
                                                     float* __restrict__ out) {
  // 3*(15488+1152) = 49920 B LDS -> still 2 blocks/CU (512 blocks = 2/CU exactly)
  __shared__ __align__(16) float zbuf[NBUF][ZCHUNK];
  __shared__ __align__(16) float xbuf[NBUF][XCHUNK];

  const int b    = blockIdx.x;
  const int t    = threadIdx.x;
  const int wave = t >> 6;
  const int lane = t & 63;

  const float* zb = z + (size_t)b * (CC * ZCH);
  const float* xb = x + (size_t)b * (CC * XCH);

  // Prologue: prefetch chunks 0,1,2 (2-deep beyond the one being computed).
  stage_chunk(zbuf[0], xbuf[0], zb, xb, wave, lane);
  stage_chunk(zbuf[1], xbuf[1], zb + ZCHUNK, xb + XCHUNK, wave, lane);
  stage_chunk(zbuf[2], xbuf[2], zb + 2 * ZCHUNK, xb + 2 * XCHUNK, wave, lane);

  // Compute mapping: 272 active threads = 16 groups x 17 output rows.
  // group g = (channel-within-chunk cl 0..7) x (ky half 0..1)
  const int  g      = t / 17;
  const int  oy     = t - g * 17;
  const int  cl     = g & 7;
  const int  kyh    = g >> 3;           // 0: ky 0..2, 1: ky 3..5
  const bool active = (g < 16);

  float acc[HO];
#pragma unroll
  for (int i = 0; i < HO; ++i) acc[i] = 0.0f;

  for (int k = 0; k < NCHUNK; ++k) {
    const int buf = k % 3;

    // Wait for chunk k's loads only; chunks k+1,k+2 stay in flight (counted
    // vmcnt, per-wave instruction counts: waves 0-2 issue 4/chunk, 3-4 issue 3).
    const int rem = NCHUNK - 1 - k;     // chunks that may remain outstanding
    if (rem >= 2) {
      if (wave < 3) WAITVM(8); else WAITVM(6);
    } else if (rem == 1) {
      if (wave < 3) WAITVM(4); else WAITVM(3);
    } else {
      WAITVM(0);
    }
    __builtin_amdgcn_s_barrier();       // all waves' chunk-k data now in LDS

    if (active) {
      const float* zc = &zbuf[buf][cl * ZCH];
      const float* xc = &xbuf[buf][cl * XCH + kyh * (3 * KXX)];

      __align__(16) float xv[3 * KXX];
#pragma unroll
      for (int i = 0; i < 9; ++i)
        ((float2*)xv)[i] = ((const float2*)xc)[i];   // ds_read_b64, broadcast-ish

#pragma unroll
      for (int ky2 = 0; ky2 < 3; ++ky2) {
        const int row = oy + kyh * 3 + ky2;
        const float* zr = zc + row * KZZ;
        __align__(16) float zv[KZZ + 1];
#pragma unroll
        for (int i = 0; i < 11; ++i)
          ((float2*)zv)[i] = ((const float2*)zr)[i]; // 11 ds_read_b64, row in regs
#pragma unroll
        for (int kx = 0; kx < KXX; ++kx) {
          const float xs = xv[ky2 * KXX + kx];
#pragma unroll
          for (int ox = 0; ox < HO; ++ox)
            acc[ox] = fmaf(zv[ox + kx], xs, acc[ox]); // 17-wide register reuse
        }
      }
    }

    __builtin_amdgcn_s_barrier();       // all waves done reading buf before restage
    if (k + 3 < NCHUNK)
      stage_chunk(zbuf[buf], xbuf[buf],
                  zb + (size_t)(k + 3) * ZCHUNK, xb + (size_t)(k + 3) * XCHUNK,
                  wave, lane);
  }

  // Cross-group reduction: 16 partials per output. Reuse zbuf as scratch.
  __syncthreads();
  float* red = &zbuf[0][0];   // needs 16*289 = 4624 floats <= 11616 available
  if (active) {
#pragma unroll
    for (int ox = 0; ox < HO; ++ox)
      red[g * OUTHW + oy * HO + ox] = acc[ox];
  }
  __syncthreads();
  if (t < OUTHW) {
    float s = 0.0f;
#pragma unroll
    for (int gg = 0; gg < 16; ++gg) s += red[gg * OUTHW + t];
    out[(size_t)b * OUTHW + t] = s;   // coalesced: consecutive t -> consecutive addr
  }
}

extern "C" void kernel_launch(void* const* d_in, const int* in_sizes, int n_in,
                              void* d_out, int out_size, void* d_ws, size_t ws_size,
                              hipStream_t stream) {
  const float* x = (const float*)d_in[0];   // [512,256,6,6]
  const float* z = (const float*)d_in[1];   // [512,256,22,22]
  float* out = (float*)d_out;               // [512,1,17,17]
  corr_kernel<<<BB, NT, 0, stream>>>(x, z, out);
}

// Round 4
// 365.882 us; speedup vs baseline: 1.0949x; 1.0949x over previous
//
#include <hip/hip_runtime.h>
#include <cstdint>
#include <cstddef>

// Problem constants (from reference)
#define BB      512
#define CC      256
#define KXX     6
#define KZZ     22
#define HO      17                 // 22 - 6 + 1
#define OUTHW   (HO * HO)          // 289
#define ZCH     (KZZ * KZZ)        // 484 floats per (b,c) of z
#define XCH     (KXX * KXX)        // 36 floats per (b,c) of x

// Tiling
#define CHUNK_C   8                          // channels staged per chunk
#define NCHUNK    (CC / CHUNK_C)             // 32
#define ZCHUNK    (CHUNK_C * ZCH)            // 3872 floats = 15488 B
#define XCHUNK    (CHUNK_C * XCH)            // 288 floats  = 1152 B
#define NT        384                        // waves 0-4 compute (272 active), wave 5 = producer
#define PRODW     5                          // producer wave index
#define NBUF      4                          // ring buffer, 2-chunk-deep prefetch
// vmem instructions per staged chunk (producer wave): 15 cp16 z + 1 cp4 z-tail
//                                                    + 1 cp16 x + 1 cp4 x-tail = 18
// WAITVM(36) = allow 2 chunks outstanding; WAITVM(18) = 1; WAITVM(0) = drain.

typedef const __attribute__((address_space(1))) void* gptr_t;
typedef __attribute__((address_space(3))) void* lptr_t;

// Counted wait on the PRODUCER's own vmem queue only. Consumers never issue
// vmem loads in the loop, so their (compiler-inserted) drains are free.
#define WAITVM(N) asm volatile("s_waitcnt vmcnt(" #N ")" ::: "memory")

// Async global->LDS. LDS dest is WAVE-UNIFORM base; HW scatters lane i to
// base + i*size. Global addr is per-lane.
__device__ __forceinline__ void cp16_async(void* lds_base, const void* gsrc) {
  __builtin_amdgcn_global_load_lds((gptr_t)gsrc, (lptr_t)lds_base, 16, 0, 0);
}
__device__ __forceinline__ void cp4_async(void* lds_base, const void* gsrc) {
  __builtin_amdgcn_global_load_lds((gptr_t)gsrc, (lptr_t)lds_base, 4, 0, 0);
}

// Single-wave stage of one chunk (18 vmem instructions):
// z = 15488 B (15 x 1 KiB + 128 B tail), x = 1152 B (1 KiB + 128 B tail).
__device__ __forceinline__ void stage_chunk_1w(float* zdst, float* xdst,
                                               const float* zsrc, const float* xsrc,
                                               int lane) {
  char* zd = (char*)zdst;
  const char* zs = (const char*)zsrc;
#pragma unroll
  for (int i = 0; i < 15; ++i)
    cp16_async(zd + i * 1024, zs + i * 1024 + lane * 16);
  if (lane < 32) cp4_async(zd + 15360, zs + 15360 + lane * 4);     // z tail 128 B
  cp16_async((char*)xdst, (const char*)xsrc + lane * 16);          // x 1024 B
  if (lane < 32) cp4_async((char*)xdst + 1024, (const char*)xsrc + 1024 + lane * 4);
}

__global__ __launch_bounds__(NT, 2) void corr_kernel(const float* __restrict__ x,
                                                     const float* __restrict__ z,
                                                     float* __restrict__ out) {
  // 4*(15488+1152) = 66560 B LDS -> 2 blocks/CU (512 blocks = 2 per CU exactly)
  __shared__ __align__(16) float zbuf[NBUF][ZCHUNK];
  __shared__ __align__(16) float xbuf[NBUF][XCHUNK];

  const int b    = blockIdx.x;
  const int t    = threadIdx.x;
  const int wave = t >> 6;
  const int lane = t & 63;

  const float* zb = z + (size_t)b * (CC * ZCH);
  const float* xb = x + (size_t)b * (CC * XCH);

  // Prologue: producer stages chunks 0 and 1.
  if (wave == PRODW) {
    stage_chunk_1w(zbuf[0], xbuf[0], zb, xb, lane);
    stage_chunk_1w(zbuf[1], xbuf[1], zb + ZCHUNK, xb + XCHUNK, lane);
  }

  // Compute mapping: 272 active threads = 16 groups x 17 output rows.
  // group g = (channel-within-chunk cl 0..7) x (ky half 0..1)
  const int  g      = t / 17;
  const int  oy     = t - g * 17;
  const int  cl     = g & 7;
  const int  kyh    = (g >> 3) & 1;     // 0: ky 0..2, 1: ky 3..5
  const bool active = (g < 16);         // waves 0-4 only; wave 5 never computes

  float acc[HO];
#pragma unroll
  for (int i = 0; i < HO; ++i) acc[i] = 0.0f;

  for (int k = 0; k < NCHUNK; ++k) {
    const int buf = k & 3;

    if (wave == PRODW) {
      // Producer: issue chunk k+2 (overwrites buf[(k+2)&3], last read in
      // iter k-2, strictly before barrier k-1 -> safe), then counted wait
      // so that chunk k is fully in LDS. Chunks k+1,k+2 stay in flight:
      // the queue never drains in the main loop (T4).
      if (k + 2 < NCHUNK) {
        stage_chunk_1w(zbuf[(k + 2) & 3], xbuf[(k + 2) & 3],
                       zb + (size_t)(k + 2) * ZCHUNK,
                       xb + (size_t)(k + 2) * XCHUNK, lane);
        WAITVM(36);                      // chunk k done; k+1,k+2 in flight
      } else if (k + 2 == NCHUNK) {      // k == 30
        WAITVM(18);                      // chunk 30 done; 31 in flight
      } else {                           // k == 31
        WAITVM(0);                       // chunk 31 done
      }
      __builtin_amdgcn_s_barrier();      // raw: do NOT drain producer queue
    } else {
      // Consumers: no vmem loads in-loop -> the implied vmcnt(0) is free;
      // full fence stops LDS reads hoisting above the barrier.
      __syncthreads();
    }

    if (active) {
      const float* zc = &zbuf[buf][cl * ZCH];
      const float* xc = &xbuf[buf][cl * XCH + kyh * (3 * KXX)];

      __align__(16) float xv[3 * KXX];
#pragma unroll
      for (int i = 0; i < 9; ++i)
        ((float2*)xv)[i] = ((const float2*)xc)[i];   // ds_read_b64, broadcast-ish

#pragma unroll
      for (int ky2 = 0; ky2 < 3; ++ky2) {
        const int row = oy + kyh * 3 + ky2;
        const float* zr = zc + row * KZZ;
        __align__(16) float zv[KZZ + 1];
#pragma unroll
        for (int i = 0; i < 11; ++i)
          ((float2*)zv)[i] = ((const float2*)zr)[i]; // 11 ds_read_b64, row in regs
#pragma unroll
        for (int kx = 0; kx < KXX; ++kx) {
          const float xs = xv[ky2 * KXX + kx];
#pragma unroll
          for (int ox = 0; ox < HO; ++ox)
            acc[ox] = fmaf(zv[ox + kx], xs, acc[ox]); // 17-wide register reuse
        }
      }
    }
  }

  // Cross-group reduction: 16 partials per output. Reuse zbuf as scratch.
  __syncthreads();
  float* red = &zbuf[0][0];   // needs 16*289 = 4624 floats, plenty available
  if (active) {
#pragma unroll
    for (int ox = 0; ox < HO; ++ox)
      red[g * OUTHW + oy * HO + ox] = acc[ox];
  }
  __syncthreads();
  if (t < OUTHW) {
    float s = 0.0f;
#pragma unroll
    for (int gg = 0; gg < 16; ++gg) s += red[gg * OUTHW + t];
    out[(size_t)b * OUTHW + t] = s;   // coalesced: consecutive t -> consecutive addr
  }
}

extern "C" void kernel_launch(void* const* d_in, const int* in_sizes, int n_in,
                              void* d_out, int out_size, void* d_ws, size_t ws_size,
                              hipStream_t stream) {
  const float* x = (const float*)d_in[0];   // [512,256,6,6]
  const float* z = (const float*)d_in[1];   // [512,256,22,22]
  float* out = (float*)d_out;               // [512,1,17,17]
  corr_kernel<<<BB, NT, 0, stream>>>(x, z, out);
}

// Round 5
// 361.828 us; speedup vs baseline: 1.1072x; 1.0112x over previous
//
#include <hip/hip_runtime.h>
#include <cstdint>
#include <cstddef>

// Problem constants (from reference)
#define BB      512
#define CC      256
#define KXX     6
#define KZZ     22
#define HO      17                 // 22 - 6 + 1
#define OUTHW   (HO * HO)          // 289
#define ZCH     (KZZ * KZZ)        // 484 floats per (b,c) of z
#define XCH     (KXX * KXX)        // 36 floats per (b,c) of x

// Tiling
#define CHUNK_C   8                          // channels staged per chunk
#define NCHUNK    (CC / CHUNK_C)             // 32
#define ZCHUNK    (CHUNK_C * ZCH)            // 3872 floats = 15488 B
#define XCHUNK    (CHUNK_C * XCH)            // 288 floats  = 1152 B
#define NT        320                        // 5 waves

// Roofline note (rounds 0-4): steady state is HBM-delivery-bound.
// Per CU: 2 blocks x 16.6 KB/chunk vs ~10.3 B/cy fair share -> ~3.2k cy/chunk
// delivery vs ~1.7k cy compute. Occupancy split (r1), counted vmcnt (r3) and
// producer-consumer wave specialization (r4) were all null or negative; the
// barrier drain and a producer's counted wait resolve at the same
// delivery-limited instant. SQ_LDS_BANK_CONFLICT (1.6e7) is free 2-way b64
// pair aliasing (m136); zv bank-start distribution is at the b64 floor.

typedef const __attribute__((address_space(1))) void* gptr_t;
typedef __attribute__((address_space(3))) void* lptr_t;

// Async global->LDS. LDS dest is WAVE-UNIFORM base; HW scatters lane i to
// base + i*size. Global addr is per-lane.
__device__ __forceinline__ void cp16_async(void* lds_base, const void* gsrc) {
  __builtin_amdgcn_global_load_lds((gptr_t)gsrc, (lptr_t)lds_base, 16, 0, 0);
}
__device__ __forceinline__ void cp4_async(void* lds_base, const void* gsrc) {
  __builtin_amdgcn_global_load_lds((gptr_t)gsrc, (lptr_t)lds_base, 4, 0, 0);
}

// Stage one chunk: z = 15488 B (15 x 1024 B + 128 B tail),
//                  x = 1152 B  (1 x 1024 B + 128 B tail).
__device__ __forceinline__ void stage_chunk(float* zdst, float* xdst,
                                            const float* zsrc, const float* xsrc,
                                            int wave, int lane) {
  char* zd = (char*)zdst;
  const char* zs = (const char*)zsrc;
#pragma unroll
  for (int i = 0; i < 3; ++i) {               // 15 full 1 KiB groups, 3 per wave
    const int grp = wave * 3 + i;
    cp16_async(zd + grp * 1024, zs + grp * 1024 + lane * 16);
  }
  if (wave == 0) {
    if (lane < 32) cp4_async(zd + 15360, zs + 15360 + lane * 4);   // z tail 128 B
  } else if (wave == 1) {
    cp16_async((char*)xdst, (const char*)xsrc + lane * 16);        // x 1024 B
  } else if (wave == 2) {
    if (lane < 32) cp4_async((char*)xdst + 1024, (const char*)xsrc + 1024 + lane * 4);
  }
}

__global__ __launch_bounds__(NT, 2) void corr_kernel(const float* __restrict__ x,
                                                     const float* __restrict__ z,
                                                     float* __restrict__ out) {
  // 2*15488 + 2*1152 = 33280 B LDS -> 2 blocks/CU (512 blocks = 2 per CU exactly)
  __shared__ __align__(16) float zbuf[2][ZCHUNK];
  __shared__ __align__(16) float xbuf[2][XCHUNK];

  const int b    = blockIdx.x;
  const int t    = threadIdx.x;
  const int wave = t >> 6;
  const int lane = t & 63;

  const float* zb = z + (size_t)b * (CC * ZCH);
  const float* xb = x + (size_t)b * (CC * XCH);

  // Prefetch chunk 0
  stage_chunk(zbuf[0], xbuf[0], zb, xb, wave, lane);

  // Compute mapping: 272 active threads = 16 groups x 17 output rows.
  // group g = (channel-within-chunk cl 0..7) x (ky half 0..1)
  const int  g      = t / 17;
  const int  oy     = t - g * 17;
  const int  cl     = g & 7;
  const int  kyh    = g >> 3;           // 0: ky 0..2, 1: ky 3..5
  const bool active = (g < 16);

  float acc[HO];
#pragma unroll
  for (int i = 0; i < HO; ++i) acc[i] = 0.0f;

  for (int k = 0; k < NCHUNK; ++k) {
    const int buf = k & 1;
    __syncthreads();   // drains chunk-k loads (vmcnt) + all LDS reads of buf^1

    // Prefetch next chunk into the other buffer; stays in flight during compute.
    if (k + 1 < NCHUNK)
      stage_chunk(zbuf[buf ^ 1], xbuf[buf ^ 1],
                  zb + (size_t)(k + 1) * ZCHUNK, xb + (size_t)(k + 1) * XCHUNK,
                  wave, lane);

    if (active) {
      const float* zc = &zbuf[buf][cl * ZCH];
      const float* xc = &xbuf[buf][cl * XCH + kyh * (3 * KXX)];

      __align__(16) float xv[3 * KXX];
#pragma unroll
      for (int i = 0; i < 9; ++i)
        ((float2*)xv)[i] = ((const float2*)xc)[i];   // ds_read_b64, broadcast-ish

#pragma unroll
      for (int ky2 = 0; ky2 < 3; ++ky2) {
        const int row = oy + kyh * 3 + ky2;
        const float* zr = zc + row * KZZ;
        __align__(16) float zv[KZZ + 1];
#pragma unroll
        for (int i = 0; i < 11; ++i)
          ((float2*)zv)[i] = ((const float2*)zr)[i]; // 11 ds_read_b64, row in regs
#pragma unroll
        for (int kx = 0; kx < KXX; ++kx) {
          const float xs = xv[ky2 * KXX + kx];
#pragma unroll
          for (int ox = 0; ox < HO; ++ox)
            acc[ox] = fmaf(zv[ox + kx], xs, acc[ox]); // 17-wide register reuse
        }
      }
    }
  }

  // Cross-group reduction: 16 partials per output. Reuse zbuf as scratch.
  __syncthreads();
  float* red = &zbuf[0][0];   // needs 16*289 = 4624 floats <= 7744 available
  if (active) {
#pragma unroll
    for (int ox = 0; ox < HO; ++ox)
      red[g * OUTHW + oy * HO + ox] = acc[ox];
  }
  __syncthreads();
  if (t < OUTHW) {
    float s = 0.0f;
#pragma unroll
    for (int gg = 0; gg < 16; ++gg) s += red[gg * OUTHW + t];
    out[(size_t)b * OUTHW + t] = s;   // coalesced: consecutive t -> consecutive addr
  }
}

extern "C" void kernel_launch(void* const* d_in, const int* in_sizes, int n_in,
                              void* d_out, int out_size, void* d_ws, size_t ws_size,
                              hipStream_t stream) {
  const float* x = (const float*)d_in[0];   // [512,256,6,6]
  const float* z = (const float*)d_in[1];   // [512,256,22,22]
  float* out = (float*)d_out;               // [512,1,17,17]
  corr_kernel<<<BB, NT, 0, stream>>>(x, z, out);
}